// Round 11
// baseline (217.117 us; speedup 1.0000x reference)
//
#include <hip/hip_runtime.h>
#include <stdint.h>

// B=16 H=8 L=512 D=64; fp32 in/out. out = concat(output[128,512,64], attn[128,512,512]).
// Round-15 = Round-14 base (best: 214.8us) with ONE isolated change:
//   QK staging depth-1 (2x32KB dbuf) -> depth-3 (4x16KB quad-buf, 64-row
//   half-chunks). The awaited batch was issued 3 phases earlier -> L2/DMA
//   latency covered ~3x. PV/softmax/stores/prep byte-identical; ledger:
//   QK phases all vmcnt(8); V0/V1 pre-issued at phases 5/6; PV c=0 vmcnt(4),
//   c>=1 vmcnt(8) as before. Same barrier count; numerics identical.
#define Ln 512
#define Dn 64
#define BHn 128
#define AOFF ((size_t)BHn*Ln*Dn)

typedef __attribute__((ext_vector_type(8))) short short8;   // 8 bf16 (4 VGPRs)
typedef __attribute__((ext_vector_type(4))) float f32x4;
typedef __attribute__((ext_vector_type(2))) float f32x2;
typedef __attribute__((ext_vector_type(4))) unsigned int u32x4;
typedef __attribute__((ext_vector_type(2))) unsigned int u32x2;

__device__ __forceinline__ uint16_t f2bf(float f){
  uint32_t x = __float_as_uint(f);
  return (uint16_t)((x + 0x7FFFu + ((x>>16)&1u)) >> 16);   // RNE
}
__device__ __forceinline__ float bf2f(uint16_t u){ return __uint_as_float(((uint32_t)u)<<16); }
__device__ __forceinline__ uint32_t pack2(float a, float b){
  return (uint32_t)f2bf(a) | ((uint32_t)f2bf(b)<<16);
}
__device__ __forceinline__ void gld16(const uint16_t* g, uint16_t* l){
  __builtin_amdgcn_global_load_lds(
      (const __attribute__((address_space(1))) void*)g,
      (__attribute__((address_space(3))) void*)l, 16, 0, 0);
}

// ---- pre-pass (verbatim round-14): K -> KHI/KLO bf16, V -> V^T bf16, swizzled ----
// K layout (halves): idx = (bh<<15) + j*64 + (k ^ ((j&7)<<3))
// V layout (halves): idx = (bh<<15) + (c<<13) + d*128 + (jl ^ ((d&7)<<3))
extern "C" __global__ __launch_bounds__(256)
void attn_prep(const float* __restrict__ kg, const float* __restrict__ vg,
               uint16_t* __restrict__ khw, uint16_t* __restrict__ klw,
               uint16_t* __restrict__ vtw)
{
  const int t    = threadIdx.x;
  const int lin  = blockIdx.x + (blockIdx.y << 4);
  const int xcd  = lin & 7;
  const int rest = lin >> 3;           // [0,256)
  const int bh   = (xcd << 4) + (rest >> 4);
  const int sub  = rest & 15;
  const int c    = sub >> 2;           // j-chunk of 128
  const int q    = sub & 3;            // 32-row quarter
  const size_t base = (size_t)bh*(Ln*Dn);
  const size_t wsb  = ((size_t)bh<<15) + ((size_t)c<<13);   // chunk base (halves)

  // K: 32 rows x 64 k; thread -> row sj, 8-wide k group
  {
    const int sj = q*32 + (t>>3);
    const int k0 = (t&7)*8;
    const float* kr = kg + base + (size_t)(c*128 + sj)*Dn + k0;
    const int sx = (sj&7)<<3;
    f32x4 x0 = *(const f32x4*)(kr);
    f32x4 x1 = *(const f32x4*)(kr + 4);
    uint32_t hw[4], lw[4];
    #pragma unroll
    for (int pi=0; pi<4; ++pi){
      float a0 = (pi<2) ? x0[pi*2]   : x1[(pi-2)*2];
      float a1 = (pi<2) ? x0[pi*2+1] : x1[(pi-2)*2+1];
      uint16_t h0 = f2bf(a0), h1 = f2bf(a1);
      hw[pi] = (uint32_t)h0 | ((uint32_t)h1<<16);
      lw[pi] = (uint32_t)f2bf(a0 - bf2f(h0)) | ((uint32_t)f2bf(a1 - bf2f(h1))<<16);
    }
    const size_t di = wsb + (size_t)sj*64 + (k0 ^ sx);
    *(u32x4*)(khw + di) = (u32x4){hw[0],hw[1],hw[2],hw[3]};
    *(u32x4*)(klw + di) = (u32x4){lw[0],lw[1],lw[2],lw[3]};
  }

  // V: 4 rows x 2 d per thread -> VT[d][jl], swizzled
  {
    const int j0 = q*32 + (t>>5)*4;
    const int d0 = (t&31)*2;
    const float* vr = vg + base + (size_t)(c*128 + j0)*Dn + d0;
    f32x2 r0 = *(const f32x2*)(vr);
    f32x2 r1 = *(const f32x2*)(vr + Dn);
    f32x2 r2 = *(const f32x2*)(vr + 2*Dn);
    f32x2 r3 = *(const f32x2*)(vr + 3*Dn);
    #pragma unroll
    for (int qd=0; qd<2; ++qd){
      const int d = d0 + qd;
      u32x2 w; w.x = pack2(r0[qd], r1[qd]); w.y = pack2(r2[qd], r3[qd]);
      *(u32x2*)(vtw + wsb + d*128 + (j0 ^ ((d&7)<<3))) = w;
    }
  }
}

// ---- main: 64 q-rows/block, 4 waves x 16 rows; QK quad-buffered depth-3 ----
extern "C" __global__ __launch_bounds__(256, 2)
void attn_main2(const float* __restrict__ qg, const float* __restrict__ mg,
                const uint16_t* __restrict__ khw, const uint16_t* __restrict__ klw,
                const uint16_t* __restrict__ vtw, float* __restrict__ outg)
{
  // 64KB BIG (halves): QK: 4 K bufs of 8192 (KH 4096 + KL 4096), buf b = [b*8192,+8192)
  //   PV (aliased): VT0 [0:8192) (=buf0), VT1 [8192:16384) (=buf1);
  //                 PW [16384:25088) (4 waves x 2176) over buf2/buf3 (K-free by then)
  // + CMV[512] f32 column-mask terms
  __shared__ __align__(16) uint16_t BIG[32768];
  __shared__ float CMV[512];

  const int t    = threadIdx.x;
  const int lane = t & 63;
  const int wv   = t >> 6;
  const int li   = lane & 15;
  const int lq   = lane >> 4;
  const int kx   = (li&7)<<3;          // swizzle XOR (halves)

  // XCD swizzle: lin%8 = XCD; XCD k owns bh [k*16,k*16+16)
  const int lin = blockIdx.x + (blockIdx.y << 3);
  const int xcd = lin & 7;
  const int jj  = lin >> 3;
  const int bh  = (xcd << 4) + (jj >> 3);
  const int b   = bh >> 3;
  const int i0  = (jj & 7)*64 + wv*16;

  const size_t base = (size_t)bh*(Ln*Dn);
  const float* mrow = mg + b*Ln;
  const size_t wsbh = (size_t)bh << 15;

  uint16_t* PW = BIG + 16384 + wv*2176;

  auto issueK = [&](int hc){            // 4 vmem ops/wave; half-chunk of 64 rows
    const size_t so = wsbh + ((size_t)hc<<12) + (wv<<10) + (lane<<3);
    uint16_t* dh = BIG + (hc&3)*8192 + (wv<<10);
    #pragma unroll
    for (int i=0;i<2;++i){
      gld16(khw + so + i*512, dh + i*512);
      gld16(klw + so + i*512, dh + 4096 + i*512);
    }
  };
  auto issueV = [&](int c, int bsel){   // 4 vmem ops/wave; chunk of 128 rows
    const size_t so = wsbh + ((size_t)c<<13) + (wv<<11) + (lane<<3);
    uint16_t* dv = BIG + bsel*8192 + (wv<<11);
    #pragma unroll
    for (int i=0;i<4;++i) gld16(vtw + so + i*512, dv + i*512);
  };

  // ---- prologue: Q + mask loads FIRST, then depth-3 K DMA ----
  const float* qrow = qg + base + (size_t)(i0 + li)*Dn;
  f32x4 qx0a = *(const f32x4*)(qrow + lq*8);
  f32x4 qx0b = *(const f32x4*)(qrow + lq*8 + 4);
  f32x4 qx1a = *(const f32x4*)(qrow + 32 + lq*8);
  f32x4 qx1b = *(const f32x4*)(qrow + 32 + lq*8 + 4);
  float m0 = mrow[t], m1 = mrow[t+256];
  float mv = mrow[i0 + li];

  issueK(0); issueK(1); issueK(2);      // 12 ops in flight

  CMV[t]     = (m0 < -9000.f) ? 1e9f : m0;
  CMV[t+256] = (m1 < -9000.f) ? 1e9f : m1;
  const float rmv = (mv < -9000.f) ? 1e9f : mv;

  short8 qhi[2], qlo[2];
  #pragma unroll
  for (int kt=0; kt<2; ++kt){
    f32x4 xa = kt ? qx1a : qx0a;
    f32x4 xb = kt ? qx1b : qx0b;
    #pragma unroll
    for (int e=0; e<8; ++e){
      float x = (e<4) ? xa[e] : xb[e-4];
      uint16_t h = f2bf(x);
      qhi[kt][e] = (short)h;
      qlo[kt][e] = (short)f2bf(x - bf2f(h));
    }
  }

  f32x4 acc[32];
  #pragma unroll
  for (int j=0; j<32; ++j) acc[j] = (f32x4)0.f;

  // ---- QK: 8 half-chunks, quad-buffered, depth-3; ONE barrier per phase ----
  // Ledger/wave: phase hc waits vmcnt(8) (2 newer K batches, or K7: V0+V1).
  // Issue K(hc+3) after the barrier (its buf's last reader was phase hc-1).
  // Phase 5 -> V0 (buf0 K-free after phase 4); phase 6 -> V1 (buf1 free after 5).
  #pragma unroll
  for (int hc=0; hc<8; ++hc){
    asm volatile("s_waitcnt vmcnt(8)" ::: "memory");
    __builtin_amdgcn_sched_barrier(0);
    __builtin_amdgcn_s_barrier();              // all waves' portions landed; also proves
    __builtin_amdgcn_sched_barrier(0);         //   buf (hc+3)&3 readers (phase hc-1) done
    if (hc<5)       issueK(hc+3);
    else if (hc==5) issueV(0, 0);
    else if (hc==6) issueV(1, 1);
    __builtin_amdgcn_sched_barrier(0);
    const uint16_t* KHp = BIG + (hc&3)*8192;
    const uint16_t* KLp = KHp + 4096;
    __builtin_amdgcn_s_setprio(1);
    #pragma unroll
    for (int jtl=0; jtl<4; ++jtl){             // half-chunk local tiles; global jt = hc*4+jtl
      #pragma unroll
      for (int kt=0; kt<2; ++kt){
        const int idx = (jtl*16 + li)*64 + ((kt*32 + lq*8) ^ kx);
        short8 kh = *(const short8*)(KHp + idx);
        short8 kl = *(const short8*)(KLp + idx);
        f32x4 A = acc[hc*4+jtl];
        A = __builtin_amdgcn_mfma_f32_16x16x32_bf16(kh, qhi[kt], A, 0,0,0);
        A = __builtin_amdgcn_mfma_f32_16x16x32_bf16(kl, qhi[kt], A, 0,0,0);
        A = __builtin_amdgcn_mfma_f32_16x16x32_bf16(kh, qlo[kt], A, 0,0,0);
        acc[hc*4+jtl] = A;
      }
    }
    __builtin_amdgcn_s_setprio(0);
  }

  // ---- mask + scale (CMV from LDS; V0/V1 DMA untouched) ----
  #pragma unroll
  for (int jt=0; jt<32; ++jt){
    f32x4 cm = *(const f32x4*)(CMV + jt*16 + lq*4);
    #pragma unroll
    for (int r=0; r<4; ++r)
      acc[jt][r] = (acc[jt][r]*0.125f - rmv) - cm[r];   // fp32 order matches ref
  }

  // ---- softmax over j (wave-local: lane owns full row across quads) ----
  float mx = -3.4e38f;
  #pragma unroll
  for (int jt=0; jt<32; ++jt)
    #pragma unroll
    for (int r=0; r<4; ++r) mx = fmaxf(mx, acc[jt][r]);
  mx = fmaxf(mx, __shfl_xor(mx, 16));
  mx = fmaxf(mx, __shfl_xor(mx, 32));
  float sum = 0.f;
  #pragma unroll
  for (int jt=0; jt<32; ++jt)
    #pragma unroll
    for (int r=0; r<4; ++r){ float e = __expf(acc[jt][r]-mx); acc[jt][r] = e; sum += e; }
  sum += __shfl_xor(sum, 16);
  sum += __shfl_xor(sum, 32);
  const float inv = 1.0f/sum;
  #pragma unroll
  for (int jt=0; jt<32; ++jt) acc[jt] = acc[jt]*inv;   // normalized P (also attn output)

  // ---- PV: VT0/VT1 ping-pong (V0/V1 pre-issued); interleaved attn stores ----
  // Ledger/wave: c=0 wait vmcnt(4) (V0 landed, V1 flies); c>=1 wait vmcnt(8)
  // (V_c landed; prev chunk's 8 stores fly). V2 issued at c=1, V3 at c=2.
  f32x4 oacc[4];
  #pragma unroll
  for (int dt=0; dt<4; ++dt) oacc[dt] = (f32x4)0.f;

  float* arow = outg + AOFF + (size_t)bh*Ln*Ln + (size_t)(i0+li)*Ln;

  #pragma unroll
  for (int c=0; c<4; ++c){
    // P pack hoisted: pure VALU on ready acc
    u32x2 pwreg[8];
    #pragma unroll
    for (int jtl=0; jtl<8; ++jtl){
      const f32x4 p = acc[c*8+jtl];
      pwreg[jtl].x = pack2(p[0], p[1]);
      pwreg[jtl].y = pack2(p[2], p[3]);
    }
    if (c==0) asm volatile("s_waitcnt vmcnt(4)" ::: "memory");
    else      asm volatile("s_waitcnt vmcnt(8)" ::: "memory");
    __builtin_amdgcn_sched_barrier(0);
    __builtin_amdgcn_s_barrier();               // all waves; gates VT buf reuse
    __builtin_amdgcn_sched_barrier(0);
    if (c==1) issueV(2, 0);                     // VT0 readers (c=0) done per this barrier
    if (c==2) issueV(3, 1);                     // VT1 readers (c=1) done
    #pragma unroll
    for (int jtl=0; jtl<8; ++jtl)               // P chunk rows (wave-private)
      *(u32x2*)(PW + li*136 + jtl*16 + lq*4) = pwreg[jtl];
    asm volatile("s_waitcnt lgkmcnt(0)" ::: "memory");   // P visible within wave
    __builtin_amdgcn_sched_barrier(0);
    const uint16_t* VTp = BIG + (c&1)*8192;
    __builtin_amdgcn_s_setprio(1);
    #pragma unroll
    for (int c32=0; c32<4; ++c32){
      short8 pf = *(const short8*)(PW + li*136 + c32*32 + lq*8);           // P^T B-frag
      #pragma unroll
      for (int dt=0; dt<4; ++dt){
        short8 vb = *(const short8*)(VTp + (dt*16+li)*128 + ((c32*32+lq*8) ^ kx)); // V^T A-frag
        oacc[dt] = __builtin_amdgcn_mfma_f32_16x16x32_bf16(vb, pf, oacc[dt], 0,0,0);
      }
    }
    __builtin_amdgcn_s_setprio(0);
    // attn stores for chunk c (normal stores; L2 merges 64B pieces into lines)
    #pragma unroll
    for (int jtl=0; jtl<8; ++jtl)
      *(f32x4*)(arow + (c*8+jtl)*16 + lq*4) = acc[c*8+jtl];
  }

  // ---- store O (O^T C-layout) ----
  #pragma unroll
  for (int dt=0; dt<4; ++dt)
    *(f32x4*)(outg + base + (size_t)(i0+li)*Dn + dt*16 + lq*4) = oacc[dt];
}

// ---------------- fallback (round-5 kernel) if workspace is too small ----------------
#define KSTR  72
#define VTSTR 136
#define FPSTRH 136

extern "C" __global__ __launch_bounds__(256, 2)
void attn_mfma(const float* __restrict__ qg, const float* __restrict__ kg,
               const float* __restrict__ vg, const float* __restrict__ mg,
               float* __restrict__ outg)
{
  __shared__ uint4 ldsraw[(36864 + 2048)/16];
  uint16_t* KHI = (uint16_t*)ldsraw;
  uint16_t* KLO = KHI + 128*KSTR;
  uint16_t* VT  = (uint16_t*)ldsraw;
  float*    CMV = (float*)((char*)ldsraw + 36864);

  const int t    = threadIdx.x;
  const int lane = t & 63;
  const int wv   = t >> 6;
  const int li   = lane & 15;
  const int lq   = lane >> 4;

  const int lin = blockIdx.x + (blockIdx.y << 3);
  const int xcd = lin & 7;
  const int jj  = lin >> 3;
  const int bh  = (xcd << 4) + (jj >> 3);
  const int b   = bh >> 3;
  const int i0  = (jj & 7)*64 + wv*16;

  const size_t base = (size_t)bh*(Ln*Dn);
  const float* mrow = mg + b*Ln;

  uint16_t* PW = (uint16_t*)((char*)ldsraw + 17408 + wv*(16*FPSTRH*2));

  {
    float m0 = mrow[t], m1 = mrow[t+256];
    CMV[t]     = (m0 < -9000.f) ? 1e9f : m0;
    CMV[t+256] = (m1 < -9000.f) ? 1e9f : m1;
  }

  short8 qhi[2], qlo[2];
  {
    const float* qrow = qg + base + (size_t)(i0 + li)*Dn;
    #pragma unroll
    for (int kt=0; kt<2; ++kt){
      const float* p = qrow + kt*32 + lq*8;
      f32x4 x0 = *(const f32x4*)p;
      f32x4 x1 = *(const f32x4*)(p+4);
      #pragma unroll
      for (int e=0; e<8; ++e){
        float x = (e<4) ? x0[e] : x1[e-4];
        uint16_t h = f2bf(x);
        qhi[kt][e] = (short)h;
        qlo[kt][e] = (short)f2bf(x - bf2f(h));
      }
    }
  }

  f32x4 acc[32];
  #pragma unroll
  for (int j=0; j<32; ++j) acc[j] = (f32x4)0.f;

  const int sj = t>>1, skh = t&1;
  #pragma unroll
  for (int c=0; c<4; ++c){
    __syncthreads();
    {
      const float* kr = kg + base + (size_t)(c*128 + sj)*Dn + skh*32;
      uint16_t* dhi = KHI + sj*KSTR + skh*32;
      uint16_t* dlo = KLO + sj*KSTR + skh*32;
      #pragma unroll
      for (int w2=0; w2<4; ++w2){
        f32x4 x0 = *(const f32x4*)(kr + w2*8);
        f32x4 x1 = *(const f32x4*)(kr + w2*8 + 4);
        uint32_t hw[4], lw[4];
        #pragma unroll
        for (int pi=0; pi<4; ++pi){
          float a0 = (pi<2) ? x0[pi*2]   : x1[(pi-2)*2];
          float a1 = (pi<2) ? x0[pi*2+1] : x1[(pi-2)*2+1];
          uint16_t h0 = f2bf(a0), h1 = f2bf(a1);
          hw[pi] = (uint32_t)h0 | ((uint32_t)h1<<16);
          lw[pi] = (uint32_t)f2bf(a0 - bf2f(h0)) | ((uint32_t)f2bf(a1 - bf2f(h1))<<16);
        }
        *(u32x4*)(dhi + w2*8) = (u32x4){hw[0],hw[1],hw[2],hw[3]};
        *(u32x4*)(dlo + w2*8) = (u32x4){lw[0],lw[1],lw[2],lw[3]};
      }
    }
    __syncthreads();
    #pragma unroll
    for (int jt=0; jt<8; ++jt){
      #pragma unroll
      for (int kt=0; kt<2; ++kt){
        const int off = (jt*16 + li)*KSTR + kt*32 + lq*8;
        short8 kh = *(const short8*)(KHI + off);
        short8 kl = *(const short8*)(KLO + off);
        f32x4 A = acc[c*8+jt];
        A = __builtin_amdgcn_mfma_f32_16x16x32_bf16(kh, qhi[kt], A, 0,0,0);
        A = __builtin_amdgcn_mfma_f32_16x16x32_bf16(kl, qhi[kt], A, 0,0,0);
        A = __builtin_amdgcn_mfma_f32_16x16x32_bf16(kh, qlo[kt], A, 0,0,0);
        acc[c*8+jt] = A;
      }
    }
  }

  {
    float mv = mrow[i0 + li];
    const float rmv = (mv < -9000.f) ? 1e9f : mv;
    #pragma unroll
    for (int jt=0; jt<32; ++jt){
      f32x4 cm = *(const f32x4*)(CMV + jt*16 + lq*4);
      #pragma unroll
      for (int r=0; r<4; ++r)
        acc[jt][r] = (acc[jt][r]*0.125f - rmv) - cm[r];
    }
  }
  float mx = -3.4e38f;
  #pragma unroll
  for (int jt=0; jt<32; ++jt)
    #pragma unroll
    for (int r=0; r<4; ++r) mx = fmaxf(mx, acc[jt][r]);
  mx = fmaxf(mx, __shfl_xor(mx, 16));
  mx = fmaxf(mx, __shfl_xor(mx, 32));
  float sum = 0.f;
  #pragma unroll
  for (int jt=0; jt<32; ++jt)
    #pragma unroll
    for (int r=0; r<4; ++r){ float e = __expf(acc[jt][r]-mx); acc[jt][r] = e; sum += e; }
  sum += __shfl_xor(sum, 16);
  sum += __shfl_xor(sum, 32);
  const float inv = 1.0f/sum;

  {
    float* arow = outg + AOFF + (size_t)bh*Ln*Ln + (size_t)(i0+li)*Ln;
    #pragma unroll
    for (int jt=0; jt<32; ++jt){
      f32x4 p = acc[jt]*inv;
      acc[jt] = p;
      *(f32x4*)(arow + jt*16 + lq*4) = p;
    }
  }

  f32x4 oacc[4];
  #pragma unroll
  for (int dt=0; dt<4; ++dt) oacc[dt] = (f32x4)0.f;

  #pragma unroll
  for (int c=0; c<4; ++c){
    __syncthreads();
    #pragma unroll
    for (int it=0; it<2; ++it){
      const int j0 = (t>>4)*4 + it*64;
      const int d0 = (t&15)*4;
      const float* vr = vg + base + (size_t)(c*128 + j0)*Dn + d0;
      f32x4 r0 = *(const f32x4*)(vr);
      f32x4 r1 = *(const f32x4*)(vr + Dn);
      f32x4 r2 = *(const f32x4*)(vr + 2*Dn);
      f32x4 r3 = *(const f32x4*)(vr + 3*Dn);
      #pragma unroll
      for (int qd=0; qd<4; ++qd){
        u32x2 w; w.x = pack2(r0[qd], r1[qd]); w.y = pack2(r2[qd], r3[qd]);
        *(u32x2*)(VT + (d0+qd)*VTSTR + j0) = w;
      }
    }
    __syncthreads();
    #pragma unroll
    for (int jtl=0; jtl<8; ++jtl){
      const f32x4 p = acc[c*8+jtl];
      u32x2 w; w.x = pack2(p[0], p[1]); w.y = pack2(p[2], p[3]);
      *(u32x2*)(PW + li*FPSTRH + jtl*16 + lq*4) = w;
    }
    asm volatile("s_waitcnt lgkmcnt(0)" ::: "memory");
    #pragma unroll
    for (int c32=0; c32<4; ++c32){
      short8 pf = *(const short8*)(PW + li*FPSTRH + c32*32 + lq*8);
      #pragma unroll
      for (int dt=0; dt<4; ++dt){
        short8 vb = *(const short8*)(VT + (dt*16+li)*VTSTR + c32*32 + lq*8);
        oacc[dt] = __builtin_amdgcn_mfma_f32_16x16x32_bf16(vb, pf, oacc[dt], 0,0,0);
      }
    }
  }

  #pragma unroll
  for (int dt=0; dt<4; ++dt)
    *(f32x4*)(outg + base + (size_t)(i0+li)*Dn + dt*16 + lq*4) = oacc[dt];
}

extern "C" void kernel_launch(void* const* d_in, const int* in_sizes, int n_in,
                              void* d_out, int out_size, void* d_ws, size_t ws_size,
                              hipStream_t stream)
{
  (void)in_sizes; (void)n_in; (void)out_size;
  const float* qg = (const float*)d_in[0];
  const float* kg = (const float*)d_in[1];
  const float* vg = (const float*)d_in[2];
  const float* mg = (const float*)d_in[3];
  float* outg = (float*)d_out;

  const size_t WS_NEED = 25165824;   // KHI 8.39MB + KLO 8.39MB + VT 8.39MB
  if (d_ws && ws_size >= WS_NEED){
    uint16_t* khw = (uint16_t*)d_ws;
    uint16_t* klw = (uint16_t*)((char*)d_ws + 8388608);
    uint16_t* vtw = (uint16_t*)((char*)d_ws + 16777216);
    attn_prep<<<dim3(16, BHn), 256, 0, stream>>>(kg, vg, khw, klw, vtw);
    attn_main2<<<dim3(Ln/64, BHn), 256, 0, stream>>>(qg, mg, khw, klw, vtw, outg);
  } else {
    attn_mfma<<<dim3(Ln/64, BHn), 256, 0, stream>>>(qg, kg, vg, mg, outg);
  }
}